// Round 11
// baseline (172.620 us; speedup 1.0000x reference)
//
#include <hip/hip_runtime.h>
#include <cstdint>

// Problem constants: N=8192, T=1024, CD=4, H=2, KD=VD=8, DA=8, AOD=16, LAT=64, OUT=32.
//
// Register-allocator model (measured R1-R10): monolithic/long-tail bodies ->
// allocator targets 64 VGPR and spills the excess (33-425MB scratch);
// fully-unrolled prefetch bodies -> balloons to 124 VGPR, occupancy 21.6%
// (R10 regression). R9 (32 VGPR, depth~2) = 58us. R11: manual depth-4
// pipeline, named buffers, macro-loop kept rolled, live ~60, and
// __launch_bounds__(512,8) pins VGPR<=64 (above live set -> no spill,
// forbids balloon).

__device__ __forceinline__ float bflo(uint32_t u) { return __uint_as_float(u << 16); }
__device__ __forceinline__ float bfhi(uint32_t u) { return __uint_as_float(u & 0xFFFF0000u); }
__device__ __forceinline__ uint32_t f2bf(float f) {
    uint32_t x = __float_as_uint(f);
    return (x + 0x7FFFu + ((x >> 16) & 1u)) >> 16;   // RNE
}
__device__ __forceinline__ float ftanh(float x) {
    float e = __expf(2.0f * x);
    return 1.0f - 2.0f / (e + 1.0f);   // stable for +-inf of e
}

// ---------------- phase 1: masked attention -> attn[n,16] ----------------
__global__ __launch_bounds__(512, 8)
void attn_phase1(const float* __restrict__ coord1,
                 const float* __restrict__ att_coeff,
                 const float* __restrict__ local_coords,
                 const void*  __restrict__ maskp,
                 const float* __restrict__ Wq, const float* __restrict__ Bq,
                 const float* __restrict__ Wk, const float* __restrict__ Bk,
                 const float* __restrict__ Wv, const float* __restrict__ Bv,
                 float* __restrict__ ws)
{
    __shared__ uint4    vq[2048];        // v table, bf16x2 packed, swizzled (32 KB)
    __shared__ uint32_t mrow[8][256];    // per-wave mask row as bytes (8 KB)

    const int tid  = threadIdx.x;
    const int lane = tid & 63;
    const int wid  = tid >> 6;           // 0..7

    // mask element size: 4-byte (int/float 0/1) vs 1-byte (bool)
    uint4 mm = ((const uint4*)maskp)[tid];
    bool ok = (mm.x <= 1u || mm.x == 0x3F800000u) &&
              (mm.y <= 1u || mm.y == 0x3F800000u) &&
              (mm.z <= 1u || mm.z == 0x3F800000u) &&
              (mm.w <= 1u || mm.w == 0x3F800000u);
    const bool m4 = (__all(ok) != 0);

    // stage v = att_coeff @ Wv + Bv (bf16x2, XOR-swizzled); 2 t's per thread
    #pragma unroll
    for (int tt = 0; tt < 2; ++tt) {
        const int t = tid * 2 + tt;
        const float4 a0 = *(const float4*)(att_coeff + t * 8);
        const float4 a1 = *(const float4*)(att_coeff + t * 8 + 4);
        float vr[16];
        #pragma unroll
        for (int o = 0; o < 16; ++o) {
            vr[o] = Bv[o]
                + a0.x * Wv[o]      + a0.y * Wv[16 + o] + a0.z * Wv[32 + o] + a0.w * Wv[48 + o]
                + a1.x * Wv[64 + o] + a1.y * Wv[80 + o] + a1.z * Wv[96 + o] + a1.w * Wv[112 + o];
        }
        #pragma unroll
        for (int h = 0; h < 2; ++h) {
            const int g  = 2 * t + h;
            const int gs = (g & ~7) | ((g ^ (g >> 3)) & 7);
            uint4 pk;
            pk.x = f2bf(vr[h * 8 + 0]) | (f2bf(vr[h * 8 + 1]) << 16);
            pk.y = f2bf(vr[h * 8 + 2]) | (f2bf(vr[h * 8 + 3]) << 16);
            pk.z = f2bf(vr[h * 8 + 4]) | (f2bf(vr[h * 8 + 5]) << 16);
            pk.w = f2bf(vr[h * 8 + 6]) | (f2bf(vr[h * 8 + 7]) << 16);
            vq[gs] = pk;
        }
    }

    const int n = (blockIdx.x << 3) + wid;     // one row per wave

    // stage this row's mask into LDS as bytes (nonzero = keep)
    if (m4) {
        const uint4* wp = (const uint4*)((const uint32_t*)maskp + (size_t)n * 1024) + lane * 4;
        uint4 pk;
        uint32_t b[4];
        #pragma unroll
        for (int j = 0; j < 4; ++j) {
            const uint4 w = wp[j];
            b[j] = (w.x ? 1u : 0u) | ((w.y ? 1u : 0u) << 8) |
                   ((w.z ? 1u : 0u) << 16) | ((w.w ? 1u : 0u) << 24);
        }
        pk.x = b[0]; pk.y = b[1]; pk.z = b[2]; pk.w = b[3];
        *(uint4*)&mrow[wid][lane * 4] = pk;
    } else {
        const uint4 w = ((const uint4*)((const uint8_t*)maskp + (size_t)n * 1024))[lane];
        *(uint4*)&mrow[wid][lane * 4] = w;
    }
    __syncthreads();

    // v-table group base for t = lane (i adds 128 per step; low-3 swizzle i-invariant)
    const int g0 = 2 * lane;
    const int bg = (g0 & ~7) | ((g0 ^ (g0 >> 3)) & 7);   // head0: vq[bg+128i]; head1: ^1
    const float rs8 = 0.35355339059327373f;              // 1/sqrt(KD)

    // both heads' q -> folded A[2][4], Bs[2]
    float A[2][4], Bs[2];
    {
        const float4 c1 = *(const float4*)(coord1 + n * 4);
        float q[16];
        #pragma unroll
        for (int o = 0; o < 16; ++o)
            q[o] = Bq[o] + c1.x * Wq[o] + c1.y * Wq[16 + o] + c1.z * Wq[32 + o] + c1.w * Wq[48 + o];
        #pragma unroll
        for (int h = 0; h < 2; ++h) {
            #pragma unroll
            for (int c = 0; c < 4; ++c) {
                float s = 0.f;
                #pragma unroll
                for (int d = 0; d < 8; ++d) s += q[h * 8 + d] * Wk[c * 16 + h * 8 + d];
                A[h][c] = s * rs8;
            }
            float s2 = 0.f;
            #pragma unroll
            for (int d = 0; d < 8; ++d) s2 += q[h * 8 + d] * Bk[h * 8 + d];
            Bs[h] = s2 * rs8;
        }
    }

    // ---- stream T: t = lane + 64*i, 16 iters, manual depth-4 pipeline ----
    const float4* lcp = (const float4*)local_coords + (size_t)n * 1024 + lane;
    const int  mword = lane >> 2;            // word in mrow (+16 per i)
    const int  msh   = (lane & 3) * 8;

    float p[16];
    #pragma unroll
    for (int k = 0; k < 16; ++k) p[k] = 0.f;
    float s0 = 0.f, s1 = 0.f;

#define STEP(BUF, I)                                                         \
    {                                                                        \
        const float4 lc = BUF;                                               \
        const uint32_t mw = mrow[wid][mword + 16 * (I)];                     \
        const bool keep = ((mw >> msh) & 0xFFu) != 0u;                       \
        const float v0 = Bs[0] + lc.x * A[0][0] + lc.y * A[0][1]             \
                               + lc.z * A[0][2] + lc.w * A[0][3];            \
        const float v1 = Bs[1] + lc.x * A[1][0] + lc.y * A[1][1]             \
                               + lc.z * A[1][2] + lc.w * A[1][3];            \
        const float e0 = keep ? __expf(v0) : 0.f;                            \
        const float e1 = keep ? __expf(v1) : 0.f;                            \
        s0 += e0; s1 += e1;                                                  \
        const uint4 w0 = vq[(bg + ((I) << 7))];                              \
        const uint4 w1 = vq[(bg + ((I) << 7)) ^ 1];                          \
        p[0]  += e0 * bflo(w0.x); p[1]  += e0 * bfhi(w0.x);                  \
        p[2]  += e0 * bflo(w0.y); p[3]  += e0 * bfhi(w0.y);                  \
        p[4]  += e0 * bflo(w0.z); p[5]  += e0 * bfhi(w0.z);                  \
        p[6]  += e0 * bflo(w0.w); p[7]  += e0 * bfhi(w0.w);                  \
        p[8]  += e1 * bflo(w1.x); p[9]  += e1 * bfhi(w1.x);                  \
        p[10] += e1 * bflo(w1.y); p[11] += e1 * bfhi(w1.y);                  \
        p[12] += e1 * bflo(w1.z); p[13] += e1 * bfhi(w1.z);                  \
        p[14] += e1 * bflo(w1.w); p[15] += e1 * bfhi(w1.w);                  \
    }

    float4 b0 = lcp[0 * 64], b1 = lcp[1 * 64], b2 = lcp[2 * 64], b3 = lcp[3 * 64];

    #pragma unroll 1   // keep the macro loop rolled: bounds register growth
    for (int ib = 0; ib < 3; ++ib) {
        const int base = ib * 4;
        STEP(b0, base + 0); b0 = lcp[(base + 4) * 64];
        STEP(b1, base + 1); b1 = lcp[(base + 5) * 64];
        STEP(b2, base + 2); b2 = lcp[(base + 6) * 64];
        STEP(b3, base + 3); b3 = lcp[(base + 7) * 64];
    }
    // epilogue: consume the last 4 (no reloads -> no OOB reads past row 8191)
    STEP(b0, 12); STEP(b1, 13); STEP(b2, 14); STEP(b3, 15);
#undef STEP

    // full-wave sums
    #pragma unroll
    for (int s = 32; s; s >>= 1) {
        s0 += __shfl_xor(s0, s, 64);
        s1 += __shfl_xor(s1, s, 64);
    }

    // all-masked fallback: uniform weights (p is exactly 0 in that case)
    if (s0 == 0.0f) {
        #pragma unroll 2
        for (int i = 0; i < 16; ++i) {
            const uint4 w0 = vq[(bg + (i << 7))];
            const uint4 w1 = vq[(bg + (i << 7)) ^ 1];
            p[0]  += bflo(w0.x); p[1]  += bfhi(w0.x);
            p[2]  += bflo(w0.y); p[3]  += bfhi(w0.y);
            p[4]  += bflo(w0.z); p[5]  += bfhi(w0.z);
            p[6]  += bflo(w0.w); p[7]  += bfhi(w0.w);
            p[8]  += bflo(w1.x); p[9]  += bfhi(w1.x);
            p[10] += bflo(w1.y); p[11] += bfhi(w1.y);
            p[12] += bflo(w1.z); p[13] += bfhi(w1.z);
            p[14] += bflo(w1.w); p[15] += bfhi(w1.w);
        }
        s0 = 1024.0f; s1 = 1024.0f;
    }

    // split butterfly (R2-verified): lane 4c ends owning attn[c], c=lane>>2
    {
        const bool h5 = (lane & 32) != 0;
        #pragma unroll
        for (int k = 0; k < 8; ++k) {
            const float snd = h5 ? p[k] : p[k + 8];
            const float kp  = h5 ? p[k + 8] : p[k];
            p[k] = kp + __shfl_xor(snd, 32, 64);
        }
        const bool h4 = (lane & 16) != 0;
        #pragma unroll
        for (int k = 0; k < 4; ++k) {
            const float snd = h4 ? p[k] : p[k + 4];
            const float kp  = h4 ? p[k + 4] : p[k];
            p[k] = kp + __shfl_xor(snd, 16, 64);
        }
        const bool h3 = (lane & 8) != 0;
        #pragma unroll
        for (int k = 0; k < 2; ++k) {
            const float snd = h3 ? p[k] : p[k + 2];
            const float kp  = h3 ? p[k + 2] : p[k];
            p[k] = kp + __shfl_xor(snd, 8, 64);
        }
        const bool h2 = (lane & 4) != 0;
        {
            const float snd = h2 ? p[0] : p[1];
            const float kp  = h2 ? p[1] : p[0];
            p[0] = kp + __shfl_xor(snd, 4, 64);
        }
        p[0] += __shfl_xor(p[0], 2, 64);
        p[0] += __shfl_xor(p[0], 1, 64);
    }

    if ((lane & 3) == 0)
        ws[(size_t)n * 16 + (lane >> 2)] = p[0] / (lane >= 32 ? s1 : s0);
}

// ---------------- phase 2: Wo/exp + tanh MLP ----------------
__global__ void attn_phase2(const float* __restrict__ coord1,
                            const float* __restrict__ coord2,
                            const float* __restrict__ ws,
                            const float* __restrict__ Wo, const float* __restrict__ Bo,
                            const float* __restrict__ W1, const float* __restrict__ B1,
                            const float* __restrict__ W2, const float* __restrict__ B2,
                            const float* __restrict__ Wt, const float* __restrict__ Bt,
                            float* __restrict__ out)
{
    const int lane = threadIdx.x & 63;
    const int wid  = threadIdx.x >> 6;
    const int n    = (blockIdx.x << 2) + wid;  // one row per wave

    const float4 c1 = *(const float4*)(coord1 + n * 4);
    const float4 c2 = *(const float4*)(coord2 + n * 4);
    const float  av = ws[(size_t)n * 16 + (lane & 15)];   // lane c<16 holds attn[c]

    // att[j] = exp(-(attn . Wo[:,j] + Bo[j])), j = lane&15
    float attv;
    {
        const int j = lane & 15;
        float acc = Bo[j];
        #pragma unroll
        for (int c = 0; c < 16; ++c)
            acc += __shfl(av, c, 64) * Wo[c * 16 + j];
        attv = __expf(-acc);
    }

    // layer 1: act1[lane] = tanh([c1,c2,att] . W1[:,lane] + B1[lane])
    float a1;
    {
        float acc = B1[lane];
        acc += c1.x * W1[0 * 64 + lane] + c1.y * W1[1 * 64 + lane]
             + c1.z * W1[2 * 64 + lane] + c1.w * W1[3 * 64 + lane];
        acc += c2.x * W1[4 * 64 + lane] + c2.y * W1[5 * 64 + lane]
             + c2.z * W1[6 * 64 + lane] + c2.w * W1[7 * 64 + lane];
        #pragma unroll
        for (int c = 0; c < 16; ++c)
            acc += __shfl(attv, c, 64) * W1[(8 + c) * 64 + lane];
        a1 = ftanh(acc);
    }

    // layer 2: act2[lane] = tanh(act1 . W2[:,lane] + B2[lane])
    float a2;
    {
        float acc = B2[lane];
        #pragma unroll
        for (int c = 0; c < 64; ++c)
            acc += __shfl(a1, c, 64) * W2[c * 64 + lane];
        a2 = ftanh(acc);
    }

    // layer 3: out[lane&31] = tanh(act2 . Wt[:,lane&31] + Bt[lane&31])
    {
        const int j = lane & 31;
        float acc = Bt[j];
        #pragma unroll
        for (int c = 0; c < 64; ++c)
            acc += __shfl(a2, c, 64) * Wt[c * 32 + j];
        if (lane < 32) out[(size_t)n * 32 + lane] = ftanh(acc);
    }
}

extern "C" void kernel_launch(void* const* d_in, const int* in_sizes, int n_in,
                              void* d_out, int out_size, void* d_ws, size_t ws_size,
                              hipStream_t stream) {
    (void)in_sizes; (void)n_in; (void)out_size; (void)ws_size;
    float* ws = (float*)d_ws;   // 8192*16 floats = 512 KB
    attn_phase1<<<1024, 512, 0, stream>>>(
        (const float*)d_in[0],  (const float*)d_in[2],
        (const float*)d_in[3],  d_in[4],
        (const float*)d_in[5],  (const float*)d_in[6],
        (const float*)d_in[7],  (const float*)d_in[8],
        (const float*)d_in[9],  (const float*)d_in[10],
        ws);
    attn_phase2<<<2048, 256, 0, stream>>>(
        (const float*)d_in[0],  (const float*)d_in[1],
        ws,
        (const float*)d_in[11], (const float*)d_in[12],
        (const float*)d_in[13], (const float*)d_in[14],
        (const float*)d_in[15], (const float*)d_in[16],
        (const float*)d_in[17], (const float*)d_in[18],
        (float*)d_out);
}

// Round 12
// 63.288 us; speedup vs baseline: 2.7276x; 2.7276x over previous
//
#include <hip/hip_runtime.h>
#include <cstdint>

// Problem constants: N=8192, T=1024, CD=4, H=2, KD=VD=8, DA=8, AOD=16, LAT=64, OUT=32.
//
// Allocator model (R1-R11, measured): rolled loops carrying VMEM results or
// long tails -> spill (33-425MB scratch); full-unroll prefetch -> VGPR
// balloon (124, occ 21%). Only R9's shape stays clean (32 VGPR): short
// unrolled stream loop, scalar state, no bounds hints. R12: keep R9's body
// verbatim but split each row across 2 waves (8 iters/wave instead of 16) --
// the R8->R9 lever (chain halving, 1.45x) applied again via TLP, not ILP.

__device__ __forceinline__ float bflo(uint32_t u) { return __uint_as_float(u << 16); }
__device__ __forceinline__ float bfhi(uint32_t u) { return __uint_as_float(u & 0xFFFF0000u); }
__device__ __forceinline__ uint32_t f2bf(float f) {
    uint32_t x = __float_as_uint(f);
    return (x + 0x7FFFu + ((x >> 16) & 1u)) >> 16;   // RNE
}
__device__ __forceinline__ float ftanh(float x) {
    float e = __expf(2.0f * x);
    return 1.0f - 2.0f / (e + 1.0f);   // stable for +-inf of e
}

// ---------------- phase 1: masked attention -> attn[n,16] ----------------
__global__ __launch_bounds__(512)
void attn_phase1(const float* __restrict__ coord1,
                 const float* __restrict__ att_coeff,
                 const float* __restrict__ local_coords,
                 const void*  __restrict__ maskp,
                 const float* __restrict__ Wq, const float* __restrict__ Bq,
                 const float* __restrict__ Wk, const float* __restrict__ Bk,
                 const float* __restrict__ Wv, const float* __restrict__ Bv,
                 float* __restrict__ ws)
{
    __shared__ uint4    vq[2048];        // v table, bf16x2 packed, swizzled (32 KB)
    __shared__ uint32_t mrow[4][256];    // per-row mask as bytes (4 KB)
    __shared__ float    comb[8][20];     // per-wave partials: p[16], s0, s1

    const int tid  = threadIdx.x;
    const int lane = tid & 63;
    const int wid  = tid >> 6;           // 0..7
    const int r    = wid >> 1;           // row slot 0..3 (2 waves per row)
    const int half = wid & 1;            // which T-half this wave covers

    // mask element size: 4-byte (int/float 0/1) vs 1-byte (bool)
    uint4 mm = ((const uint4*)maskp)[tid];
    bool ok = (mm.x <= 1u || mm.x == 0x3F800000u) &&
              (mm.y <= 1u || mm.y == 0x3F800000u) &&
              (mm.z <= 1u || mm.z == 0x3F800000u) &&
              (mm.w <= 1u || mm.w == 0x3F800000u);
    const bool m4 = (__all(ok) != 0);

    // stage v = att_coeff @ Wv + Bv (bf16x2, XOR-swizzled); 2 t's per thread
    #pragma unroll
    for (int tt = 0; tt < 2; ++tt) {
        const int t = tid * 2 + tt;
        const float4 a0 = *(const float4*)(att_coeff + t * 8);
        const float4 a1 = *(const float4*)(att_coeff + t * 8 + 4);
        float vr[16];
        #pragma unroll
        for (int o = 0; o < 16; ++o) {
            vr[o] = Bv[o]
                + a0.x * Wv[o]      + a0.y * Wv[16 + o] + a0.z * Wv[32 + o] + a0.w * Wv[48 + o]
                + a1.x * Wv[64 + o] + a1.y * Wv[80 + o] + a1.z * Wv[96 + o] + a1.w * Wv[112 + o];
        }
        #pragma unroll
        for (int h = 0; h < 2; ++h) {
            const int g  = 2 * t + h;
            const int gs = (g & ~7) | ((g ^ (g >> 3)) & 7);
            uint4 pk;
            pk.x = f2bf(vr[h * 8 + 0]) | (f2bf(vr[h * 8 + 1]) << 16);
            pk.y = f2bf(vr[h * 8 + 2]) | (f2bf(vr[h * 8 + 3]) << 16);
            pk.z = f2bf(vr[h * 8 + 4]) | (f2bf(vr[h * 8 + 5]) << 16);
            pk.w = f2bf(vr[h * 8 + 6]) | (f2bf(vr[h * 8 + 7]) << 16);
            vq[gs] = pk;
        }
    }

    const int n = (blockIdx.x << 2) + r;       // row for this wave pair

    // even wave of each pair stages the row's mask into LDS as bytes
    if (half == 0) {
        if (m4) {
            const uint4* wp = (const uint4*)((const uint32_t*)maskp + (size_t)n * 1024) + lane * 4;
            uint4 pk;
            uint32_t b[4];
            #pragma unroll
            for (int j = 0; j < 4; ++j) {
                const uint4 w = wp[j];
                b[j] = (w.x ? 1u : 0u) | ((w.y ? 1u : 0u) << 8) |
                       ((w.z ? 1u : 0u) << 16) | ((w.w ? 1u : 0u) << 24);
            }
            pk.x = b[0]; pk.y = b[1]; pk.z = b[2]; pk.w = b[3];
            *(uint4*)&mrow[r][lane * 4] = pk;
        } else {
            const uint4 w = ((const uint4*)((const uint8_t*)maskp + (size_t)n * 1024))[lane];
            *(uint4*)&mrow[r][lane * 4] = w;
        }
    }
    __syncthreads();

    // v-table group base for t = lane (i adds 128 per step; low-3 swizzle i-invariant)
    const int g0 = 2 * lane;
    const int bg = (g0 & ~7) | ((g0 ^ (g0 >> 3)) & 7);   // head0: vq[bg+128i]; head1: ^1
    const float rs8 = 0.35355339059327373f;              // 1/sqrt(KD)

    // both heads' q -> folded A[2][4], Bs[2]
    float A[2][4], Bs[2];
    {
        const float4 c1 = *(const float4*)(coord1 + n * 4);
        float q[16];
        #pragma unroll
        for (int o = 0; o < 16; ++o)
            q[o] = Bq[o] + c1.x * Wq[o] + c1.y * Wq[16 + o] + c1.z * Wq[32 + o] + c1.w * Wq[48 + o];
        #pragma unroll
        for (int h = 0; h < 2; ++h) {
            #pragma unroll
            for (int c = 0; c < 4; ++c) {
                float s = 0.f;
                #pragma unroll
                for (int d = 0; d < 8; ++d) s += q[h * 8 + d] * Wk[c * 16 + h * 8 + d];
                A[h][c] = s * rs8;
            }
            float s2 = 0.f;
            #pragma unroll
            for (int d = 0; d < 8; ++d) s2 += q[h * 8 + d] * Bk[h * 8 + d];
            Bs[h] = s2 * rs8;
        }
    }

    // ---- stream own T-half: t = lane + 64*i, i in [8*half, 8*half+8) ----
    const float4* lcp = (const float4*)local_coords + (size_t)n * 1024 + lane;
    const int  mword = lane >> 2;            // word in mrow (+16 per i)
    const int  msh   = (lane & 3) * 8;
    const int  i0    = half * 8;

    float p[16];
    #pragma unroll
    for (int k = 0; k < 16; ++k) p[k] = 0.f;
    float s0 = 0.f, s1 = 0.f;

    #pragma unroll 2
    for (int ii = 0; ii < 8; ++ii) {
        const int i = i0 + ii;
        const float4 lc = lcp[i * 64];
        const uint32_t mw = mrow[r][mword + 16 * i];
        const bool keep = ((mw >> msh) & 0xFFu) != 0u;
        const float v0 = Bs[0] + lc.x * A[0][0] + lc.y * A[0][1] + lc.z * A[0][2] + lc.w * A[0][3];
        const float v1 = Bs[1] + lc.x * A[1][0] + lc.y * A[1][1] + lc.z * A[1][2] + lc.w * A[1][3];
        const float e0 = keep ? __expf(v0) : 0.f;   // |v| bounded: no overflow
        const float e1 = keep ? __expf(v1) : 0.f;
        s0 += e0; s1 += e1;
        const uint4 w0 = vq[(bg + (i << 7))];
        const uint4 w1 = vq[(bg + (i << 7)) ^ 1];
        p[0]  += e0 * bflo(w0.x); p[1]  += e0 * bfhi(w0.x);
        p[2]  += e0 * bflo(w0.y); p[3]  += e0 * bfhi(w0.y);
        p[4]  += e0 * bflo(w0.z); p[5]  += e0 * bfhi(w0.z);
        p[6]  += e0 * bflo(w0.w); p[7]  += e0 * bfhi(w0.w);
        p[8]  += e1 * bflo(w1.x); p[9]  += e1 * bfhi(w1.x);
        p[10] += e1 * bflo(w1.y); p[11] += e1 * bfhi(w1.y);
        p[12] += e1 * bflo(w1.z); p[13] += e1 * bfhi(w1.z);
        p[14] += e1 * bflo(w1.w); p[15] += e1 * bfhi(w1.w);
    }

    // full-wave sums of this wave's partial s
    #pragma unroll
    for (int s = 32; s; s >>= 1) {
        s0 += __shfl_xor(s0, s, 64);
        s1 += __shfl_xor(s1, s, 64);
    }

    // split butterfly (R2-verified): lane 4c ends owning partial attn-num[c]
    {
        const bool h5 = (lane & 32) != 0;
        #pragma unroll
        for (int k = 0; k < 8; ++k) {
            const float snd = h5 ? p[k] : p[k + 8];
            const float kp  = h5 ? p[k + 8] : p[k];
            p[k] = kp + __shfl_xor(snd, 32, 64);
        }
        const bool h4 = (lane & 16) != 0;
        #pragma unroll
        for (int k = 0; k < 4; ++k) {
            const float snd = h4 ? p[k] : p[k + 4];
            const float kp  = h4 ? p[k + 4] : p[k];
            p[k] = kp + __shfl_xor(snd, 16, 64);
        }
        const bool h3 = (lane & 8) != 0;
        #pragma unroll
        for (int k = 0; k < 2; ++k) {
            const float snd = h3 ? p[k] : p[k + 2];
            const float kp  = h3 ? p[k + 2] : p[k];
            p[k] = kp + __shfl_xor(snd, 8, 64);
        }
        const bool h2 = (lane & 4) != 0;
        {
            const float snd = h2 ? p[0] : p[1];
            const float kp  = h2 ? p[1] : p[0];
            p[0] = kp + __shfl_xor(snd, 4, 64);
        }
        p[0] += __shfl_xor(p[0], 2, 64);
        p[0] += __shfl_xor(p[0], 1, 64);
    }

    // publish partials
    if ((lane & 3) == 0) comb[wid][lane >> 2] = p[0];
    if (lane == 0) { comb[wid][16] = s0; comb[wid][17] = s1; }
    __syncthreads();

    // even wave of each pair combines + normalizes + stores
    if (half == 0) {
        const float s0T = comb[wid][16] + comb[wid + 1][16];
        const float s1T = comb[wid][17] + comb[wid + 1][17];
        if (s0T != 0.0f) {
            if ((lane & 3) == 0) {
                const int c = lane >> 2;
                const float pT = comb[wid][c] + comb[wid + 1][c];
                ws[(size_t)n * 16 + c] = pT / (c >= 8 ? s1T : s0T);
            }
        } else {
            // all-masked row (prob ~2^-1024): softmax degenerates to uniform;
            // attn = mean_t v = (mean_t att_coeff) @ Wv + Bv, computed exactly.
            float meanA[8];
            #pragma unroll
            for (int d = 0; d < 8; ++d) {
                float acc = 0.f;
                for (int t = lane; t < 1024; t += 64) acc += att_coeff[t * 8 + d];
                #pragma unroll
                for (int s = 32; s; s >>= 1) acc += __shfl_xor(acc, s, 64);
                meanA[d] = acc * (1.0f / 1024.0f);
            }
            if ((lane & 3) == 0) {
                const int c = lane >> 2;
                float v = Bv[c];
                #pragma unroll
                for (int d = 0; d < 8; ++d) v += meanA[d] * Wv[d * 16 + c];
                ws[(size_t)n * 16 + c] = v;
            }
        }
    }
}

// ---------------- phase 2: Wo/exp + tanh MLP ----------------
__global__ void attn_phase2(const float* __restrict__ coord1,
                            const float* __restrict__ coord2,
                            const float* __restrict__ ws,
                            const float* __restrict__ Wo, const float* __restrict__ Bo,
                            const float* __restrict__ W1, const float* __restrict__ B1,
                            const float* __restrict__ W2, const float* __restrict__ B2,
                            const float* __restrict__ Wt, const float* __restrict__ Bt,
                            float* __restrict__ out)
{
    const int lane = threadIdx.x & 63;
    const int wid  = threadIdx.x >> 6;
    const int n    = (blockIdx.x << 2) + wid;  // one row per wave

    const float4 c1 = *(const float4*)(coord1 + n * 4);
    const float4 c2 = *(const float4*)(coord2 + n * 4);
    const float  av = ws[(size_t)n * 16 + (lane & 15)];   // lane c<16 holds attn[c]

    // att[j] = exp(-(attn . Wo[:,j] + Bo[j])), j = lane&15
    float attv;
    {
        const int j = lane & 15;
        float acc = Bo[j];
        #pragma unroll
        for (int c = 0; c < 16; ++c)
            acc += __shfl(av, c, 64) * Wo[c * 16 + j];
        attv = __expf(-acc);
    }

    // layer 1: act1[lane] = tanh([c1,c2,att] . W1[:,lane] + B1[lane])
    float a1;
    {
        float acc = B1[lane];
        acc += c1.x * W1[0 * 64 + lane] + c1.y * W1[1 * 64 + lane]
             + c1.z * W1[2 * 64 + lane] + c1.w * W1[3 * 64 + lane];
        acc += c2.x * W1[4 * 64 + lane] + c2.y * W1[5 * 64 + lane]
             + c2.z * W1[6 * 64 + lane] + c2.w * W1[7 * 64 + lane];
        #pragma unroll
        for (int c = 0; c < 16; ++c)
            acc += __shfl(attv, c, 64) * W1[(8 + c) * 64 + lane];
        a1 = ftanh(acc);
    }

    // layer 2: act2[lane] = tanh(act1 . W2[:,lane] + B2[lane])
    float a2;
    {
        float acc = B2[lane];
        #pragma unroll
        for (int c = 0; c < 64; ++c)
            acc += __shfl(a1, c, 64) * W2[c * 64 + lane];
        a2 = ftanh(acc);
    }

    // layer 3: out[lane&31] = tanh(act2 . Wt[:,lane&31] + Bt[lane&31])
    {
        const int j = lane & 31;
        float acc = Bt[j];
        #pragma unroll
        for (int c = 0; c < 64; ++c)
            acc += __shfl(a2, c, 64) * Wt[c * 32 + j];
        if (lane < 32) out[(size_t)n * 32 + lane] = ftanh(acc);
    }
}

extern "C" void kernel_launch(void* const* d_in, const int* in_sizes, int n_in,
                              void* d_out, int out_size, void* d_ws, size_t ws_size,
                              hipStream_t stream) {
    (void)in_sizes; (void)n_in; (void)out_size; (void)ws_size;
    float* ws = (float*)d_ws;   // 8192*16 floats = 512 KB
    attn_phase1<<<2048, 512, 0, stream>>>(
        (const float*)d_in[0],  (const float*)d_in[2],
        (const float*)d_in[3],  d_in[4],
        (const float*)d_in[5],  (const float*)d_in[6],
        (const float*)d_in[7],  (const float*)d_in[8],
        (const float*)d_in[9],  (const float*)d_in[10],
        ws);
    attn_phase2<<<2048, 256, 0, stream>>>(
        (const float*)d_in[0],  (const float*)d_in[1],
        ws,
        (const float*)d_in[11], (const float*)d_in[12],
        (const float*)d_in[13], (const float*)d_in[14],
        (const float*)d_in[15], (const float*)d_in[16],
        (const float*)d_in[17], (const float*)d_in[18],
        (float*)d_out);
}

// Round 13
// 58.413 us; speedup vs baseline: 2.9552x; 1.0834x over previous
//
#include <hip/hip_runtime.h>
#include <cstdint>

// Problem constants: N=8192, T=1024, CD=4, H=2, KD=VD=8, DA=8, AOD=16, LAT=64, OUT=32.
//
// Allocator model (R1-R12, measured): rolled loops carrying VMEM results or
// long tails -> spill; full-unroll prefetch -> VGPR balloon. Clean shape =
// R9: short unrolled stream loop, scalar state (32 VGPR). R12 (2 waves/row)
// proved TLP is NOT the lever: runtime invariant when waves x chain-halving
// cancel. R13: R9 structure verbatim, #pragma unroll 4 on the stream loop --
// compiler-managed 4-deep load batching (counted vmcnt), ~48 VGPR expected.

__device__ __forceinline__ float bflo(uint32_t u) { return __uint_as_float(u << 16); }
__device__ __forceinline__ float bfhi(uint32_t u) { return __uint_as_float(u & 0xFFFF0000u); }
__device__ __forceinline__ uint32_t f2bf(float f) {
    uint32_t x = __float_as_uint(f);
    return (x + 0x7FFFu + ((x >> 16) & 1u)) >> 16;   // RNE
}
__device__ __forceinline__ float ftanh(float x) {
    float e = __expf(2.0f * x);
    return 1.0f - 2.0f / (e + 1.0f);   // stable for +-inf of e
}

// ---------------- phase 1: masked attention -> attn[n,16] ----------------
__global__ __launch_bounds__(512)
void attn_phase1(const float* __restrict__ coord1,
                 const float* __restrict__ att_coeff,
                 const float* __restrict__ local_coords,
                 const void*  __restrict__ maskp,
                 const float* __restrict__ Wq, const float* __restrict__ Bq,
                 const float* __restrict__ Wk, const float* __restrict__ Bk,
                 const float* __restrict__ Wv, const float* __restrict__ Bv,
                 float* __restrict__ ws)
{
    __shared__ uint4    vq[2048];        // v table, bf16x2 packed, swizzled (32 KB)
    __shared__ uint32_t mrow[8][256];    // per-wave mask row as bytes (8 KB)

    const int tid  = threadIdx.x;
    const int lane = tid & 63;
    const int wid  = tid >> 6;           // 0..7

    // mask element size: 4-byte (int/float 0/1) vs 1-byte (bool)
    uint4 mm = ((const uint4*)maskp)[tid];
    bool ok = (mm.x <= 1u || mm.x == 0x3F800000u) &&
              (mm.y <= 1u || mm.y == 0x3F800000u) &&
              (mm.z <= 1u || mm.z == 0x3F800000u) &&
              (mm.w <= 1u || mm.w == 0x3F800000u);
    const bool m4 = (__all(ok) != 0);

    // stage v = att_coeff @ Wv + Bv (bf16x2, XOR-swizzled); 2 t's per thread
    #pragma unroll
    for (int tt = 0; tt < 2; ++tt) {
        const int t = tid * 2 + tt;
        const float4 a0 = *(const float4*)(att_coeff + t * 8);
        const float4 a1 = *(const float4*)(att_coeff + t * 8 + 4);
        float vr[16];
        #pragma unroll
        for (int o = 0; o < 16; ++o) {
            vr[o] = Bv[o]
                + a0.x * Wv[o]      + a0.y * Wv[16 + o] + a0.z * Wv[32 + o] + a0.w * Wv[48 + o]
                + a1.x * Wv[64 + o] + a1.y * Wv[80 + o] + a1.z * Wv[96 + o] + a1.w * Wv[112 + o];
        }
        #pragma unroll
        for (int h = 0; h < 2; ++h) {
            const int g  = 2 * t + h;
            const int gs = (g & ~7) | ((g ^ (g >> 3)) & 7);
            uint4 pk;
            pk.x = f2bf(vr[h * 8 + 0]) | (f2bf(vr[h * 8 + 1]) << 16);
            pk.y = f2bf(vr[h * 8 + 2]) | (f2bf(vr[h * 8 + 3]) << 16);
            pk.z = f2bf(vr[h * 8 + 4]) | (f2bf(vr[h * 8 + 5]) << 16);
            pk.w = f2bf(vr[h * 8 + 6]) | (f2bf(vr[h * 8 + 7]) << 16);
            vq[gs] = pk;
        }
    }

    const int n = (blockIdx.x << 3) + wid;     // one row per wave

    // stage this row's mask into LDS as bytes (nonzero = keep)
    if (m4) {
        const uint4* wp = (const uint4*)((const uint32_t*)maskp + (size_t)n * 1024) + lane * 4;
        uint4 pk;
        uint32_t b[4];
        #pragma unroll
        for (int j = 0; j < 4; ++j) {
            const uint4 w = wp[j];
            b[j] = (w.x ? 1u : 0u) | ((w.y ? 1u : 0u) << 8) |
                   ((w.z ? 1u : 0u) << 16) | ((w.w ? 1u : 0u) << 24);
        }
        pk.x = b[0]; pk.y = b[1]; pk.z = b[2]; pk.w = b[3];
        *(uint4*)&mrow[wid][lane * 4] = pk;
    } else {
        const uint4 w = ((const uint4*)((const uint8_t*)maskp + (size_t)n * 1024))[lane];
        *(uint4*)&mrow[wid][lane * 4] = w;
    }
    __syncthreads();

    // v-table group base for t = lane (i adds 128 per step; low-3 swizzle i-invariant)
    const int g0 = 2 * lane;
    const int bg = (g0 & ~7) | ((g0 ^ (g0 >> 3)) & 7);   // head0: vq[bg+128i]; head1: ^1
    const float rs8 = 0.35355339059327373f;              // 1/sqrt(KD)

    // both heads' q -> folded A[2][4], Bs[2]
    float A[2][4], Bs[2];
    {
        const float4 c1 = *(const float4*)(coord1 + n * 4);
        float q[16];
        #pragma unroll
        for (int o = 0; o < 16; ++o)
            q[o] = Bq[o] + c1.x * Wq[o] + c1.y * Wq[16 + o] + c1.z * Wq[32 + o] + c1.w * Wq[48 + o];
        #pragma unroll
        for (int h = 0; h < 2; ++h) {
            #pragma unroll
            for (int c = 0; c < 4; ++c) {
                float s = 0.f;
                #pragma unroll
                for (int d = 0; d < 8; ++d) s += q[h * 8 + d] * Wk[c * 16 + h * 8 + d];
                A[h][c] = s * rs8;
            }
            float s2 = 0.f;
            #pragma unroll
            for (int d = 0; d < 8; ++d) s2 += q[h * 8 + d] * Bk[h * 8 + d];
            Bs[h] = s2 * rs8;
        }
    }

    // ---- stream T: t = lane + 64*i, 16 iters, unroll 4 (4 loads batched) ----
    const float4* lcp = (const float4*)local_coords + (size_t)n * 1024 + lane;
    const int  mword = lane >> 2;            // word in mrow (+16 per i)
    const int  msh   = (lane & 3) * 8;

    float p[16];
    #pragma unroll
    for (int k = 0; k < 16; ++k) p[k] = 0.f;
    float s0 = 0.f, s1 = 0.f;

    #pragma unroll 4
    for (int i = 0; i < 16; ++i) {
        const float4 lc = lcp[i * 64];
        const uint32_t mw = mrow[wid][mword + 16 * i];
        const bool keep = ((mw >> msh) & 0xFFu) != 0u;
        const float v0 = Bs[0] + lc.x * A[0][0] + lc.y * A[0][1] + lc.z * A[0][2] + lc.w * A[0][3];
        const float v1 = Bs[1] + lc.x * A[1][0] + lc.y * A[1][1] + lc.z * A[1][2] + lc.w * A[1][3];
        const float e0 = keep ? __expf(v0) : 0.f;   // |v| bounded: no overflow
        const float e1 = keep ? __expf(v1) : 0.f;
        s0 += e0; s1 += e1;
        const uint4 w0 = vq[(bg + (i << 7))];
        const uint4 w1 = vq[(bg + (i << 7)) ^ 1];
        p[0]  += e0 * bflo(w0.x); p[1]  += e0 * bfhi(w0.x);
        p[2]  += e0 * bflo(w0.y); p[3]  += e0 * bfhi(w0.y);
        p[4]  += e0 * bflo(w0.z); p[5]  += e0 * bfhi(w0.z);
        p[6]  += e0 * bflo(w0.w); p[7]  += e0 * bfhi(w0.w);
        p[8]  += e1 * bflo(w1.x); p[9]  += e1 * bfhi(w1.x);
        p[10] += e1 * bflo(w1.y); p[11] += e1 * bfhi(w1.y);
        p[12] += e1 * bflo(w1.z); p[13] += e1 * bfhi(w1.z);
        p[14] += e1 * bflo(w1.w); p[15] += e1 * bfhi(w1.w);
    }

    // full-wave sums
    #pragma unroll
    for (int s = 32; s; s >>= 1) {
        s0 += __shfl_xor(s0, s, 64);
        s1 += __shfl_xor(s1, s, 64);
    }

    // all-masked fallback: uniform weights (p is exactly 0 in that case)
    if (s0 == 0.0f) {
        #pragma unroll 2
        for (int i = 0; i < 16; ++i) {
            const uint4 w0 = vq[(bg + (i << 7))];
            const uint4 w1 = vq[(bg + (i << 7)) ^ 1];
            p[0]  += bflo(w0.x); p[1]  += bfhi(w0.x);
            p[2]  += bflo(w0.y); p[3]  += bfhi(w0.y);
            p[4]  += bflo(w0.z); p[5]  += bfhi(w0.z);
            p[6]  += bflo(w0.w); p[7]  += bfhi(w0.w);
            p[8]  += bflo(w1.x); p[9]  += bfhi(w1.x);
            p[10] += bflo(w1.y); p[11] += bfhi(w1.y);
            p[12] += bflo(w1.z); p[13] += bfhi(w1.z);
            p[14] += bflo(w1.w); p[15] += bfhi(w1.w);
        }
        s0 = 1024.0f; s1 = 1024.0f;
    }

    // split butterfly (R2-verified): lane 4c ends owning attn[c], c=lane>>2
    {
        const bool h5 = (lane & 32) != 0;
        #pragma unroll
        for (int k = 0; k < 8; ++k) {
            const float snd = h5 ? p[k] : p[k + 8];
            const float kp  = h5 ? p[k + 8] : p[k];
            p[k] = kp + __shfl_xor(snd, 32, 64);
        }
        const bool h4 = (lane & 16) != 0;
        #pragma unroll
        for (int k = 0; k < 4; ++k) {
            const float snd = h4 ? p[k] : p[k + 4];
            const float kp  = h4 ? p[k + 4] : p[k];
            p[k] = kp + __shfl_xor(snd, 16, 64);
        }
        const bool h3 = (lane & 8) != 0;
        #pragma unroll
        for (int k = 0; k < 2; ++k) {
            const float snd = h3 ? p[k] : p[k + 2];
            const float kp  = h3 ? p[k + 2] : p[k];
            p[k] = kp + __shfl_xor(snd, 8, 64);
        }
        const bool h2 = (lane & 4) != 0;
        {
            const float snd = h2 ? p[0] : p[1];
            const float kp  = h2 ? p[1] : p[0];
            p[0] = kp + __shfl_xor(snd, 4, 64);
        }
        p[0] += __shfl_xor(p[0], 2, 64);
        p[0] += __shfl_xor(p[0], 1, 64);
    }

    if ((lane & 3) == 0)
        ws[(size_t)n * 16 + (lane >> 2)] = p[0] / (lane >= 32 ? s1 : s0);
}

// ---------------- phase 2: Wo/exp + tanh MLP ----------------
__global__ void attn_phase2(const float* __restrict__ coord1,
                            const float* __restrict__ coord2,
                            const float* __restrict__ ws,
                            const float* __restrict__ Wo, const float* __restrict__ Bo,
                            const float* __restrict__ W1, const float* __restrict__ B1,
                            const float* __restrict__ W2, const float* __restrict__ B2,
                            const float* __restrict__ Wt, const float* __restrict__ Bt,
                            float* __restrict__ out)
{
    const int lane = threadIdx.x & 63;
    const int wid  = threadIdx.x >> 6;
    const int n    = (blockIdx.x << 2) + wid;  // one row per wave

    const float4 c1 = *(const float4*)(coord1 + n * 4);
    const float4 c2 = *(const float4*)(coord2 + n * 4);
    const float  av = ws[(size_t)n * 16 + (lane & 15)];   // lane c<16 holds attn[c]

    // att[j] = exp(-(attn . Wo[:,j] + Bo[j])), j = lane&15
    float attv;
    {
        const int j = lane & 15;
        float acc = Bo[j];
        #pragma unroll
        for (int c = 0; c < 16; ++c)
            acc += __shfl(av, c, 64) * Wo[c * 16 + j];
        attv = __expf(-acc);
    }

    // layer 1: act1[lane] = tanh([c1,c2,att] . W1[:,lane] + B1[lane])
    float a1;
    {
        float acc = B1[lane];
        acc += c1.x * W1[0 * 64 + lane] + c1.y * W1[1 * 64 + lane]
             + c1.z * W1[2 * 64 + lane] + c1.w * W1[3 * 64 + lane];
        acc += c2.x * W1[4 * 64 + lane] + c2.y * W1[5 * 64 + lane]
             + c2.z * W1[6 * 64 + lane] + c2.w * W1[7 * 64 + lane];
        #pragma unroll
        for (int c = 0; c < 16; ++c)
            acc += __shfl(attv, c, 64) * W1[(8 + c) * 64 + lane];
        a1 = ftanh(acc);
    }

    // layer 2: act2[lane] = tanh(act1 . W2[:,lane] + B2[lane])
    float a2;
    {
        float acc = B2[lane];
        #pragma unroll
        for (int c = 0; c < 64; ++c)
            acc += __shfl(a1, c, 64) * W2[c * 64 + lane];
        a2 = ftanh(acc);
    }

    // layer 3: out[lane&31] = tanh(act2 . Wt[:,lane&31] + Bt[lane&31])
    {
        const int j = lane & 31;
        float acc = Bt[j];
        #pragma unroll
        for (int c = 0; c < 64; ++c)
            acc += __shfl(a2, c, 64) * Wt[c * 32 + j];
        if (lane < 32) out[(size_t)n * 32 + lane] = ftanh(acc);
    }
}

extern "C" void kernel_launch(void* const* d_in, const int* in_sizes, int n_in,
                              void* d_out, int out_size, void* d_ws, size_t ws_size,
                              hipStream_t stream) {
    (void)in_sizes; (void)n_in; (void)out_size; (void)ws_size;
    float* ws = (float*)d_ws;   // 8192*16 floats = 512 KB
    attn_phase1<<<1024, 512, 0, stream>>>(
        (const float*)d_in[0],  (const float*)d_in[2],
        (const float*)d_in[3],  d_in[4],
        (const float*)d_in[5],  (const float*)d_in[6],
        (const float*)d_in[7],  (const float*)d_in[8],
        (const float*)d_in[9],  (const float*)d_in[10],
        ws);
    attn_phase2<<<2048, 256, 0, stream>>>(
        (const float*)d_in[0],  (const float*)d_in[1],
        ws,
        (const float*)d_in[11], (const float*)d_in[12],
        (const float*)d_in[13], (const float*)d_in[14],
        (const float*)d_in[15], (const float*)d_in[16],
        (const float*)d_in[17], (const float*)d_in[18],
        (float*)d_out);
}

// Round 14
// 56.926 us; speedup vs baseline: 3.0323x; 1.0261x over previous
//
#include <hip/hip_runtime.h>
#include <cstdint>

// Problem constants: N=8192, T=1024, CD=4, H=2, KD=VD=8, DA=8, AOD=16, LAT=64, OUT=32.
//
// R9/R12/R13 (measured): three different concurrency shapes all at 83-87us
// profiled phase1 -- register-based pipelining is blocked by the ~64-VGPR
// spill cliff, and occupancy variation (42-58%) doesn't matter. R14: the one
// untried documented lever -- global_load_lds async ring (in-flight data
// costs 0 VGPR) + hand-counted s_waitcnt vmcnt(N) (bypasses the compiler's
// conservative per-group vmcnt(0) drains). Ring: 4 slots x 1KB per wave.

__device__ __forceinline__ float bflo(uint32_t u) { return __uint_as_float(u << 16); }
__device__ __forceinline__ float bfhi(uint32_t u) { return __uint_as_float(u & 0xFFFF0000u); }
__device__ __forceinline__ uint32_t f2bf(float f) {
    uint32_t x = __float_as_uint(f);
    return (x + 0x7FFFu + ((x >> 16) & 1u)) >> 16;   // RNE
}
__device__ __forceinline__ float ftanh(float x) {
    float e = __expf(2.0f * x);
    return 1.0f - 2.0f / (e + 1.0f);   // stable for +-inf of e
}

// ---------------- phase 1: masked attention -> attn[n,16] ----------------
__global__ __launch_bounds__(512)
void attn_phase1(const float* __restrict__ coord1,
                 const float* __restrict__ att_coeff,
                 const float* __restrict__ local_coords,
                 const void*  __restrict__ maskp,
                 const float* __restrict__ Wq, const float* __restrict__ Bq,
                 const float* __restrict__ Wk, const float* __restrict__ Bk,
                 const float* __restrict__ Wv, const float* __restrict__ Bv,
                 float* __restrict__ ws)
{
    __shared__ uint4    vq[2048];        // v table, bf16x2 packed, swizzled (32 KB)
    __shared__ uint32_t mrow[8][256];    // per-wave mask row as bytes (8 KB)
    __shared__ float4   ring[8][4][64];  // per-wave 4-slot async ring (32 KB)

    const int tid  = threadIdx.x;
    const int lane = tid & 63;
    const int wid  = tid >> 6;           // 0..7

    // mask element size: 4-byte (int/float 0/1) vs 1-byte (bool)
    uint4 mm = ((const uint4*)maskp)[tid];
    bool ok = (mm.x <= 1u || mm.x == 0x3F800000u) &&
              (mm.y <= 1u || mm.y == 0x3F800000u) &&
              (mm.z <= 1u || mm.z == 0x3F800000u) &&
              (mm.w <= 1u || mm.w == 0x3F800000u);
    const bool m4 = (__all(ok) != 0);

    // stage v = att_coeff @ Wv + Bv (bf16x2, XOR-swizzled); 2 t's per thread
    #pragma unroll
    for (int tt = 0; tt < 2; ++tt) {
        const int t = tid * 2 + tt;
        const float4 a0 = *(const float4*)(att_coeff + t * 8);
        const float4 a1 = *(const float4*)(att_coeff + t * 8 + 4);
        float vr[16];
        #pragma unroll
        for (int o = 0; o < 16; ++o) {
            vr[o] = Bv[o]
                + a0.x * Wv[o]      + a0.y * Wv[16 + o] + a0.z * Wv[32 + o] + a0.w * Wv[48 + o]
                + a1.x * Wv[64 + o] + a1.y * Wv[80 + o] + a1.z * Wv[96 + o] + a1.w * Wv[112 + o];
        }
        #pragma unroll
        for (int h = 0; h < 2; ++h) {
            const int g  = 2 * t + h;
            const int gs = (g & ~7) | ((g ^ (g >> 3)) & 7);
            uint4 pk;
            pk.x = f2bf(vr[h * 8 + 0]) | (f2bf(vr[h * 8 + 1]) << 16);
            pk.y = f2bf(vr[h * 8 + 2]) | (f2bf(vr[h * 8 + 3]) << 16);
            pk.z = f2bf(vr[h * 8 + 4]) | (f2bf(vr[h * 8 + 5]) << 16);
            pk.w = f2bf(vr[h * 8 + 6]) | (f2bf(vr[h * 8 + 7]) << 16);
            vq[gs] = pk;
        }
    }

    const int n = (blockIdx.x << 3) + wid;     // one row per wave

    // stage this row's mask into LDS as bytes (nonzero = keep)
    if (m4) {
        const uint4* wp = (const uint4*)((const uint32_t*)maskp + (size_t)n * 1024) + lane * 4;
        uint4 pk;
        uint32_t b[4];
        #pragma unroll
        for (int j = 0; j < 4; ++j) {
            const uint4 w = wp[j];
            b[j] = (w.x ? 1u : 0u) | ((w.y ? 1u : 0u) << 8) |
                   ((w.z ? 1u : 0u) << 16) | ((w.w ? 1u : 0u) << 24);
        }
        pk.x = b[0]; pk.y = b[1]; pk.z = b[2]; pk.w = b[3];
        *(uint4*)&mrow[wid][lane * 4] = pk;
    } else {
        const uint4 w = ((const uint4*)((const uint8_t*)maskp + (size_t)n * 1024))[lane];
        *(uint4*)&mrow[wid][lane * 4] = w;
    }
    __syncthreads();

    // v-table group base for t = lane (i adds 128 per step; low-3 swizzle i-invariant)
    const int g0 = 2 * lane;
    const int bg = (g0 & ~7) | ((g0 ^ (g0 >> 3)) & 7);   // head0: vq[bg+128i]; head1: ^1
    const float rs8 = 0.35355339059327373f;              // 1/sqrt(KD)

    // both heads' q -> folded A[2][4], Bs[2]
    float A[2][4], Bs[2];
    {
        const float4 c1 = *(const float4*)(coord1 + n * 4);
        float q[16];
        #pragma unroll
        for (int o = 0; o < 16; ++o)
            q[o] = Bq[o] + c1.x * Wq[o] + c1.y * Wq[16 + o] + c1.z * Wq[32 + o] + c1.w * Wq[48 + o];
        #pragma unroll
        for (int h = 0; h < 2; ++h) {
            #pragma unroll
            for (int c = 0; c < 4; ++c) {
                float s = 0.f;
                #pragma unroll
                for (int d = 0; d < 8; ++d) s += q[h * 8 + d] * Wk[c * 16 + h * 8 + d];
                A[h][c] = s * rs8;
            }
            float s2 = 0.f;
            #pragma unroll
            for (int d = 0; d < 8; ++d) s2 += q[h * 8 + d] * Bk[h * 8 + d];
            Bs[h] = s2 * rs8;
        }
    }

    // ---- stream T: t = lane + 64*i via async global->LDS ring, depth 4 ----
    const float4* lcp = (const float4*)local_coords + (size_t)n * 1024 + lane;
    const int  mword = lane >> 2;            // word in mrow (+16 per i)
    const int  msh   = (lane & 3) * 8;

    float p[16];
    #pragma unroll
    for (int k = 0; k < 16; ++k) p[k] = 0.f;
    float s0 = 0.f, s1 = 0.f;

    // prologue: 4 fire-and-forget loads (per-lane global addr, uniform LDS base)
    #pragma unroll
    for (int s = 0; s < 4; ++s)
        __builtin_amdgcn_global_load_lds((const uint32_t*)(lcp + s * 64),
                                         (uint32_t*)&ring[wid][s][0], 16, 0, 0);

#define COMPUTE(LC, I)                                                        \
    {                                                                         \
        const uint32_t mw = mrow[wid][mword + 16 * (I)];                      \
        const bool keep = ((mw >> msh) & 0xFFu) != 0u;                        \
        const float v0 = Bs[0] + (LC).x * A[0][0] + (LC).y * A[0][1]          \
                               + (LC).z * A[0][2] + (LC).w * A[0][3];         \
        const float v1 = Bs[1] + (LC).x * A[1][0] + (LC).y * A[1][1]          \
                               + (LC).z * A[1][2] + (LC).w * A[1][3];         \
        const float e0 = keep ? __expf(v0) : 0.f;                             \
        const float e1 = keep ? __expf(v1) : 0.f;                             \
        s0 += e0; s1 += e1;                                                   \
        const uint4 w0 = vq[(bg + ((I) << 7))];                               \
        const uint4 w1 = vq[(bg + ((I) << 7)) ^ 1];                           \
        p[0]  += e0 * bflo(w0.x); p[1]  += e0 * bfhi(w0.x);                   \
        p[2]  += e0 * bflo(w0.y); p[3]  += e0 * bfhi(w0.y);                   \
        p[4]  += e0 * bflo(w0.z); p[5]  += e0 * bfhi(w0.z);                   \
        p[6]  += e0 * bflo(w0.w); p[7]  += e0 * bfhi(w0.w);                   \
        p[8]  += e1 * bflo(w1.x); p[9]  += e1 * bfhi(w1.x);                   \
        p[10] += e1 * bflo(w1.y); p[11] += e1 * bfhi(w1.y);                   \
        p[12] += e1 * bflo(w1.z); p[13] += e1 * bfhi(w1.z);                   \
        p[14] += e1 * bflo(w1.w); p[15] += e1 * bfhi(w1.w);                   \
    }

    // steady state: 12 iterations with counted waits (3 loads stay in flight)
    #pragma unroll 1
    for (int i = 0; i < 12; ++i) {
        asm volatile("s_waitcnt vmcnt(3)" ::: "memory");   // oldest slot landed
        __builtin_amdgcn_sched_barrier(0);
        const float4 lc4 = ring[wid][i & 3][lane];          // ds_read_b128
        asm volatile("s_waitcnt lgkmcnt(0)" ::: "memory"); // slot free for reuse
        __builtin_amdgcn_sched_barrier(0);
        __builtin_amdgcn_global_load_lds((const uint32_t*)(lcp + (i + 4) * 64),
                                         (uint32_t*)&ring[wid][i & 3][0], 16, 0, 0);
        COMPUTE(lc4, i);
    }
    // epilogue: drain and consume last 4 slots
    asm volatile("s_waitcnt vmcnt(0)" ::: "memory");
    __builtin_amdgcn_sched_barrier(0);
    {
        const float4 lcA = ring[wid][0][lane];
        const float4 lcB = ring[wid][1][lane];
        const float4 lcC = ring[wid][2][lane];
        const float4 lcD = ring[wid][3][lane];
        COMPUTE(lcA, 12);
        COMPUTE(lcB, 13);
        COMPUTE(lcC, 14);
        COMPUTE(lcD, 15);
    }
#undef COMPUTE

    // full-wave sums
    #pragma unroll
    for (int s = 32; s; s >>= 1) {
        s0 += __shfl_xor(s0, s, 64);
        s1 += __shfl_xor(s1, s, 64);
    }

    // all-masked fallback: uniform weights (p is exactly 0 in that case)
    if (s0 == 0.0f) {
        #pragma unroll 2
        for (int i = 0; i < 16; ++i) {
            const uint4 w0 = vq[(bg + (i << 7))];
            const uint4 w1 = vq[(bg + (i << 7)) ^ 1];
            p[0]  += bflo(w0.x); p[1]  += bfhi(w0.x);
            p[2]  += bflo(w0.y); p[3]  += bfhi(w0.y);
            p[4]  += bflo(w0.z); p[5]  += bfhi(w0.z);
            p[6]  += bflo(w0.w); p[7]  += bfhi(w0.w);
            p[8]  += bflo(w1.x); p[9]  += bfhi(w1.x);
            p[10] += bflo(w1.y); p[11] += bfhi(w1.y);
            p[12] += bflo(w1.z); p[13] += bfhi(w1.z);
            p[14] += bflo(w1.w); p[15] += bfhi(w1.w);
        }
        s0 = 1024.0f; s1 = 1024.0f;
    }

    // split butterfly (R2-verified): lane 4c ends owning attn[c], c=lane>>2
    {
        const bool h5 = (lane & 32) != 0;
        #pragma unroll
        for (int k = 0; k < 8; ++k) {
            const float snd = h5 ? p[k] : p[k + 8];
            const float kp  = h5 ? p[k + 8] : p[k];
            p[k] = kp + __shfl_xor(snd, 32, 64);
        }
        const bool h4 = (lane & 16) != 0;
        #pragma unroll
        for (int k = 0; k < 4; ++k) {
            const float snd = h4 ? p[k] : p[k + 4];
            const float kp  = h4 ? p[k + 4] : p[k];
            p[k] = kp + __shfl_xor(snd, 16, 64);
        }
        const bool h3 = (lane & 8) != 0;
        #pragma unroll
        for (int k = 0; k < 2; ++k) {
            const float snd = h3 ? p[k] : p[k + 2];
            const float kp  = h3 ? p[k + 2] : p[k];
            p[k] = kp + __shfl_xor(snd, 8, 64);
        }
        const bool h2 = (lane & 4) != 0;
        {
            const float snd = h2 ? p[0] : p[1];
            const float kp  = h2 ? p[1] : p[0];
            p[0] = kp + __shfl_xor(snd, 4, 64);
        }
        p[0] += __shfl_xor(p[0], 2, 64);
        p[0] += __shfl_xor(p[0], 1, 64);
    }

    if ((lane & 3) == 0)
        ws[(size_t)n * 16 + (lane >> 2)] = p[0] / (lane >= 32 ? s1 : s0);
}

// ---------------- phase 2: Wo/exp + tanh MLP ----------------
__global__ void attn_phase2(const float* __restrict__ coord1,
                            const float* __restrict__ coord2,
                            const float* __restrict__ ws,
                            const float* __restrict__ Wo, const float* __restrict__ Bo,
                            const float* __restrict__ W1, const float* __restrict__ B1,
                            const float* __restrict__ W2, const float* __restrict__ B2,
                            const float* __restrict__ Wt, const float* __restrict__ Bt,
                            float* __restrict__ out)
{
    const int lane = threadIdx.x & 63;
    const int wid  = threadIdx.x >> 6;
    const int n    = (blockIdx.x << 2) + wid;  // one row per wave

    const float4 c1 = *(const float4*)(coord1 + n * 4);
    const float4 c2 = *(const float4*)(coord2 + n * 4);
    const float  av = ws[(size_t)n * 16 + (lane & 15)];   // lane c<16 holds attn[c]

    // att[j] = exp(-(attn . Wo[:,j] + Bo[j])), j = lane&15
    float attv;
    {
        const int j = lane & 15;
        float acc = Bo[j];
        #pragma unroll
        for (int c = 0; c < 16; ++c)
            acc += __shfl(av, c, 64) * Wo[c * 16 + j];
        attv = __expf(-acc);
    }

    // layer 1: act1[lane] = tanh([c1,c2,att] . W1[:,lane] + B1[lane])
    float a1;
    {
        float acc = B1[lane];
        acc += c1.x * W1[0 * 64 + lane] + c1.y * W1[1 * 64 + lane]
             + c1.z * W1[2 * 64 + lane] + c1.w * W1[3 * 64 + lane];
        acc += c2.x * W1[4 * 64 + lane] + c2.y * W1[5 * 64 + lane]
             + c2.z * W1[6 * 64 + lane] + c2.w * W1[7 * 64 + lane];
        #pragma unroll
        for (int c = 0; c < 16; ++c)
            acc += __shfl(attv, c, 64) * W1[(8 + c) * 64 + lane];
        a1 = ftanh(acc);
    }

    // layer 2: act2[lane] = tanh(act1 . W2[:,lane] + B2[lane])
    float a2;
    {
        float acc = B2[lane];
        #pragma unroll
        for (int c = 0; c < 64; ++c)
            acc += __shfl(a1, c, 64) * W2[c * 64 + lane];
        a2 = ftanh(acc);
    }

    // layer 3: out[lane&31] = tanh(act2 . Wt[:,lane&31] + Bt[lane&31])
    {
        const int j = lane & 31;
        float acc = Bt[j];
        #pragma unroll
        for (int c = 0; c < 64; ++c)
            acc += __shfl(a2, c, 64) * Wt[c * 32 + j];
        if (lane < 32) out[(size_t)n * 32 + lane] = ftanh(acc);
    }
}

extern "C" void kernel_launch(void* const* d_in, const int* in_sizes, int n_in,
                              void* d_out, int out_size, void* d_ws, size_t ws_size,
                              hipStream_t stream) {
    (void)in_sizes; (void)n_in; (void)out_size; (void)ws_size;
    float* ws = (float*)d_ws;   // 8192*16 floats = 512 KB
    attn_phase1<<<1024, 512, 0, stream>>>(
        (const float*)d_in[0],  (const float*)d_in[2],
        (const float*)d_in[3],  d_in[4],
        (const float*)d_in[5],  (const float*)d_in[6],
        (const float*)d_in[7],  (const float*)d_in[8],
        (const float*)d_in[9],  (const float*)d_in[10],
        ws);
    attn_phase2<<<2048, 256, 0, stream>>>(
        (const float*)d_in[0],  (const float*)d_in[1],
        ws,
        (const float*)d_in[11], (const float*)d_in[12],
        (const float*)d_in[13], (const float*)d_in[14],
        (const float*)d_in[15], (const float*)d_in[16],
        (const float*)d_in[17], (const float*)d_in[18],
        (float*)d_out);
}

// Round 15
// 52.983 us; speedup vs baseline: 3.2580x; 1.0744x over previous
//
#include <hip/hip_runtime.h>
#include <cstdint>

// Problem constants: N=8192, T=1024, CD=4, H=2, KD=VD=8, DA=8, AOD=16, LAT=64, OUT=32.
//
// R9/R12/R13/R14 (measured): six phase1 shapes all at ~51us timed / 2.8 TB/s
// effective read -- memory-service-rate bound for this pattern; per-wave
// pipeline shape is irrelevant. Remaining cost: the phase2 launch + ws
// round-trip (~5us). R15: merge the MLP tail back into phase1 (monolith was
// never tried at 1-row-per-wave without the it-loop; post-loop liveness is
// ~2 regs, tail is wave-local shuffles, c1/c2 reloaded in the tail).
// Spill signature to watch: WRITE_SIZE >> 1MB -> revert to split + roofline.

__device__ __forceinline__ float bflo(uint32_t u) { return __uint_as_float(u << 16); }
__device__ __forceinline__ float bfhi(uint32_t u) { return __uint_as_float(u & 0xFFFF0000u); }
__device__ __forceinline__ uint32_t f2bf(float f) {
    uint32_t x = __float_as_uint(f);
    return (x + 0x7FFFu + ((x >> 16) & 1u)) >> 16;   // RNE
}
__device__ __forceinline__ float ftanh(float x) {
    float e = __expf(2.0f * x);
    return 1.0f - 2.0f / (e + 1.0f);   // stable for +-inf of e
}

__global__ __launch_bounds__(512)
void attn_mlp_fused(const float* __restrict__ coord1,
                    const float* __restrict__ coord2,
                    const float* __restrict__ att_coeff,
                    const float* __restrict__ local_coords,
                    const void*  __restrict__ maskp,
                    const float* __restrict__ Wq, const float* __restrict__ Bq,
                    const float* __restrict__ Wk, const float* __restrict__ Bk,
                    const float* __restrict__ Wv, const float* __restrict__ Bv,
                    const float* __restrict__ Wo, const float* __restrict__ Bo,
                    const float* __restrict__ W1, const float* __restrict__ B1,
                    const float* __restrict__ W2, const float* __restrict__ B2,
                    const float* __restrict__ Wt, const float* __restrict__ Bt,
                    float* __restrict__ out)
{
    __shared__ uint4    vq[2048];        // v table, bf16x2 packed, swizzled (32 KB)
    __shared__ uint32_t mrow[8][256];    // per-wave mask row as bytes (8 KB)

    const int tid  = threadIdx.x;
    const int lane = tid & 63;
    const int wid  = tid >> 6;           // 0..7

    // mask element size: 4-byte (int/float 0/1) vs 1-byte (bool)
    uint4 mm = ((const uint4*)maskp)[tid];
    bool ok = (mm.x <= 1u || mm.x == 0x3F800000u) &&
              (mm.y <= 1u || mm.y == 0x3F800000u) &&
              (mm.z <= 1u || mm.z == 0x3F800000u) &&
              (mm.w <= 1u || mm.w == 0x3F800000u);
    const bool m4 = (__all(ok) != 0);

    // stage v = att_coeff @ Wv + Bv (bf16x2, XOR-swizzled); 2 t's per thread
    #pragma unroll
    for (int tt = 0; tt < 2; ++tt) {
        const int t = tid * 2 + tt;
        const float4 a0 = *(const float4*)(att_coeff + t * 8);
        const float4 a1 = *(const float4*)(att_coeff + t * 8 + 4);
        float vr[16];
        #pragma unroll
        for (int o = 0; o < 16; ++o) {
            vr[o] = Bv[o]
                + a0.x * Wv[o]      + a0.y * Wv[16 + o] + a0.z * Wv[32 + o] + a0.w * Wv[48 + o]
                + a1.x * Wv[64 + o] + a1.y * Wv[80 + o] + a1.z * Wv[96 + o] + a1.w * Wv[112 + o];
        }
        #pragma unroll
        for (int h = 0; h < 2; ++h) {
            const int g  = 2 * t + h;
            const int gs = (g & ~7) | ((g ^ (g >> 3)) & 7);
            uint4 pk;
            pk.x = f2bf(vr[h * 8 + 0]) | (f2bf(vr[h * 8 + 1]) << 16);
            pk.y = f2bf(vr[h * 8 + 2]) | (f2bf(vr[h * 8 + 3]) << 16);
            pk.z = f2bf(vr[h * 8 + 4]) | (f2bf(vr[h * 8 + 5]) << 16);
            pk.w = f2bf(vr[h * 8 + 6]) | (f2bf(vr[h * 8 + 7]) << 16);
            vq[gs] = pk;
        }
    }

    const int n = (blockIdx.x << 3) + wid;     // one row per wave (no it-loop)

    // stage this row's mask into LDS as bytes (nonzero = keep)
    if (m4) {
        const uint4* wp = (const uint4*)((const uint32_t*)maskp + (size_t)n * 1024) + lane * 4;
        uint4 pk;
        uint32_t b[4];
        #pragma unroll
        for (int j = 0; j < 4; ++j) {
            const uint4 w = wp[j];
            b[j] = (w.x ? 1u : 0u) | ((w.y ? 1u : 0u) << 8) |
                   ((w.z ? 1u : 0u) << 16) | ((w.w ? 1u : 0u) << 24);
        }
        pk.x = b[0]; pk.y = b[1]; pk.z = b[2]; pk.w = b[3];
        *(uint4*)&mrow[wid][lane * 4] = pk;
    } else {
        const uint4 w = ((const uint4*)((const uint8_t*)maskp + (size_t)n * 1024))[lane];
        *(uint4*)&mrow[wid][lane * 4] = w;
    }
    __syncthreads();

    // v-table group base for t = lane (i adds 128 per step; low-3 swizzle i-invariant)
    const int g0 = 2 * lane;
    const int bg = (g0 & ~7) | ((g0 ^ (g0 >> 3)) & 7);   // head0: vq[bg+128i]; head1: ^1
    const float rs8 = 0.35355339059327373f;              // 1/sqrt(KD)

    // both heads' q -> folded A[2][4], Bs[2]  (c1 NOT kept live through the loop)
    float A[2][4], Bs[2];
    {
        const float4 c1 = *(const float4*)(coord1 + n * 4);
        float q[16];
        #pragma unroll
        for (int o = 0; o < 16; ++o)
            q[o] = Bq[o] + c1.x * Wq[o] + c1.y * Wq[16 + o] + c1.z * Wq[32 + o] + c1.w * Wq[48 + o];
        #pragma unroll
        for (int h = 0; h < 2; ++h) {
            #pragma unroll
            for (int c = 0; c < 4; ++c) {
                float s = 0.f;
                #pragma unroll
                for (int d = 0; d < 8; ++d) s += q[h * 8 + d] * Wk[c * 16 + h * 8 + d];
                A[h][c] = s * rs8;
            }
            float s2 = 0.f;
            #pragma unroll
            for (int d = 0; d < 8; ++d) s2 += q[h * 8 + d] * Bk[h * 8 + d];
            Bs[h] = s2 * rs8;
        }
    }

    // ---- stream T: t = lane + 64*i, 16 iters, unroll 4 (R13-proven body) ----
    const float4* lcp = (const float4*)local_coords + (size_t)n * 1024 + lane;
    const int  mword = lane >> 2;
    const int  msh   = (lane & 3) * 8;

    float p[16];
    #pragma unroll
    for (int k = 0; k < 16; ++k) p[k] = 0.f;
    float s0 = 0.f, s1 = 0.f;

    #pragma unroll 4
    for (int i = 0; i < 16; ++i) {
        const float4 lc = lcp[i * 64];
        const uint32_t mw = mrow[wid][mword + 16 * i];
        const bool keep = ((mw >> msh) & 0xFFu) != 0u;
        const float v0 = Bs[0] + lc.x * A[0][0] + lc.y * A[0][1] + lc.z * A[0][2] + lc.w * A[0][3];
        const float v1 = Bs[1] + lc.x * A[1][0] + lc.y * A[1][1] + lc.z * A[1][2] + lc.w * A[1][3];
        const float e0 = keep ? __expf(v0) : 0.f;   // |v| bounded: no overflow
        const float e1 = keep ? __expf(v1) : 0.f;
        s0 += e0; s1 += e1;
        const uint4 w0 = vq[(bg + (i << 7))];
        const uint4 w1 = vq[(bg + (i << 7)) ^ 1];
        p[0]  += e0 * bflo(w0.x); p[1]  += e0 * bfhi(w0.x);
        p[2]  += e0 * bflo(w0.y); p[3]  += e0 * bfhi(w0.y);
        p[4]  += e0 * bflo(w0.z); p[5]  += e0 * bfhi(w0.z);
        p[6]  += e0 * bflo(w0.w); p[7]  += e0 * bfhi(w0.w);
        p[8]  += e1 * bflo(w1.x); p[9]  += e1 * bfhi(w1.x);
        p[10] += e1 * bflo(w1.y); p[11] += e1 * bfhi(w1.y);
        p[12] += e1 * bflo(w1.z); p[13] += e1 * bfhi(w1.z);
        p[14] += e1 * bflo(w1.w); p[15] += e1 * bfhi(w1.w);
    }

    // full-wave sums
    #pragma unroll
    for (int s = 32; s; s >>= 1) {
        s0 += __shfl_xor(s0, s, 64);
        s1 += __shfl_xor(s1, s, 64);
    }

    // all-masked fallback: uniform weights (p is exactly 0 in that case)
    if (s0 == 0.0f) {
        #pragma unroll 2
        for (int i = 0; i < 16; ++i) {
            const uint4 w0 = vq[(bg + (i << 7))];
            const uint4 w1 = vq[(bg + (i << 7)) ^ 1];
            p[0]  += bflo(w0.x); p[1]  += bfhi(w0.x);
            p[2]  += bflo(w0.y); p[3]  += bfhi(w0.y);
            p[4]  += bflo(w0.z); p[5]  += bfhi(w0.z);
            p[6]  += bflo(w0.w); p[7]  += bfhi(w0.w);
            p[8]  += bflo(w1.x); p[9]  += bfhi(w1.x);
            p[10] += bflo(w1.y); p[11] += bfhi(w1.y);
            p[12] += bflo(w1.z); p[13] += bfhi(w1.z);
            p[14] += bflo(w1.w); p[15] += bfhi(w1.w);
        }
        s0 = 1024.0f; s1 = 1024.0f;
    }

    // split butterfly (R2-verified): lanes 4c..4c+3 end holding attn-num[c]
    {
        const bool h5 = (lane & 32) != 0;
        #pragma unroll
        for (int k = 0; k < 8; ++k) {
            const float snd = h5 ? p[k] : p[k + 8];
            const float kp  = h5 ? p[k + 8] : p[k];
            p[k] = kp + __shfl_xor(snd, 32, 64);
        }
        const bool h4 = (lane & 16) != 0;
        #pragma unroll
        for (int k = 0; k < 4; ++k) {
            const float snd = h4 ? p[k] : p[k + 4];
            const float kp  = h4 ? p[k + 4] : p[k];
            p[k] = kp + __shfl_xor(snd, 16, 64);
        }
        const bool h3 = (lane & 8) != 0;
        #pragma unroll
        for (int k = 0; k < 2; ++k) {
            const float snd = h3 ? p[k] : p[k + 2];
            const float kp  = h3 ? p[k + 2] : p[k];
            p[k] = kp + __shfl_xor(snd, 8, 64);
        }
        const bool h2 = (lane & 4) != 0;
        {
            const float snd = h2 ? p[0] : p[1];
            const float kp  = h2 ? p[1] : p[0];
            p[0] = kp + __shfl_xor(snd, 4, 64);
        }
        p[0] += __shfl_xor(p[0], 2, 64);
        p[0] += __shfl_xor(p[0], 1, 64);
    }

    // normalized attn element (lane>>2) in every lane (head = lane>>5)
    const float pn = p[0] / (lane >= 32 ? s1 : s0);

    // ================= MLP tail (was phase 2; wave-local, shuffle-only) ====

    // att[j] = exp(-(attn . Wo[:,j] + Bo[j])), j = lane&15; attn[c] at lane 4c
    float attv;
    {
        const int j = lane & 15;
        float acc = Bo[j];
        #pragma unroll
        for (int c = 0; c < 16; ++c)
            acc += __shfl(pn, 4 * c, 64) * Wo[c * 16 + j];
        attv = __expf(-acc);
    }

    // reload coords fresh (L2-hot; avoids holding them live across the loop)
    const float4 c1 = *(const float4*)(coord1 + n * 4);
    const float4 c2 = *(const float4*)(coord2 + n * 4);

    // layer 1: act1[lane] = tanh([c1,c2,att] . W1[:,lane] + B1[lane])
    float a1;
    {
        float acc = B1[lane];
        acc += c1.x * W1[0 * 64 + lane] + c1.y * W1[1 * 64 + lane]
             + c1.z * W1[2 * 64 + lane] + c1.w * W1[3 * 64 + lane];
        acc += c2.x * W1[4 * 64 + lane] + c2.y * W1[5 * 64 + lane]
             + c2.z * W1[6 * 64 + lane] + c2.w * W1[7 * 64 + lane];
        #pragma unroll
        for (int c = 0; c < 16; ++c)
            acc += __shfl(attv, c, 64) * W1[(8 + c) * 64 + lane];
        a1 = ftanh(acc);
    }

    // layer 2: act2[lane] = tanh(act1 . W2[:,lane] + B2[lane])
    float a2;
    {
        float acc = B2[lane];
        #pragma unroll
        for (int c = 0; c < 64; ++c)
            acc += __shfl(a1, c, 64) * W2[c * 64 + lane];
        a2 = ftanh(acc);
    }

    // layer 3: out[lane&31] = tanh(act2 . Wt[:,lane&31] + Bt[lane&31])
    {
        const int j = lane & 31;
        float acc = Bt[j];
        #pragma unroll
        for (int c = 0; c < 64; ++c)
            acc += __shfl(a2, c, 64) * Wt[c * 32 + j];
        if (lane < 32) out[(size_t)n * 32 + lane] = ftanh(acc);
    }
}

extern "C" void kernel_launch(void* const* d_in, const int* in_sizes, int n_in,
                              void* d_out, int out_size, void* d_ws, size_t ws_size,
                              hipStream_t stream) {
    (void)in_sizes; (void)n_in; (void)out_size; (void)d_ws; (void)ws_size;
    attn_mlp_fused<<<1024, 512, 0, stream>>>(
        (const float*)d_in[0],  (const float*)d_in[1],
        (const float*)d_in[2],  (const float*)d_in[3],
        d_in[4],
        (const float*)d_in[5],  (const float*)d_in[6],
        (const float*)d_in[7],  (const float*)d_in[8],
        (const float*)d_in[9],  (const float*)d_in[10],
        (const float*)d_in[11], (const float*)d_in[12],
        (const float*)d_in[13], (const float*)d_in[14],
        (const float*)d_in[15], (const float*)d_in[16],
        (const float*)d_in[17], (const float*)d_in[18],
        (float*)d_out);
}